// Round 1
// baseline (297.047 us; speedup 1.0000x reference)
//
#include <hip/hip_runtime.h>
#include <hip/hip_bf16.h>

typedef unsigned short u16;
typedef __attribute__((ext_vector_type(8))) __bf16 v8bf;
typedef __attribute__((ext_vector_type(4))) float v4f;

#define DEVINL __device__ __forceinline__

DEVINL u16 f2bf(float f) {
  union { float f; unsigned u; } v; v.f = f;
  unsigned u = v.u;
  return (u16)((u + 0x7FFFu + ((u >> 16) & 1u)) >> 16);  // RNE
}
DEVINL float bf2f(u16 b) {
  union { unsigned u; float f; } v; v.u = ((unsigned)b) << 16;
  return v.f;
}

// async global->LDS, 16B per lane; dest is wave-uniform base + lane*16
DEVINL void async16(const void* g, void* l) {
  __builtin_amdgcn_global_load_lds(
      (__attribute__((address_space(1))) void*)(g),
      (__attribute__((address_space(3))) void*)(l), 16, 0, 0);
}

// ---------------- elementwise fp32 -> bf16 ----------------
__global__ __launch_bounds__(256) void k_f2b(const float* __restrict__ src,
                                             u16* __restrict__ dst, int n) {
  int i = (blockIdx.x * 256 + threadIdx.x) * 4;
  if (i + 3 < n) {
    float4 v = *(const float4*)(src + i);
    unsigned lo = (unsigned)f2bf(v.x) | ((unsigned)f2bf(v.y) << 16);
    unsigned hi = (unsigned)f2bf(v.z) | ((unsigned)f2bf(v.w) << 16);
    uint2 o; o.x = lo; o.y = hi;
    *(uint2*)(dst + i) = o;
  }
}

// ---------------- tiled transpose + convert: src fp32 [R][C] -> dst bf16 [C][R] ----------------
__global__ __launch_bounds__(256) void k_transpose_f2b(
    const float* __restrict__ src, u16* __restrict__ dst,
    int R, int C, long srcBatch, long dstBatch) {
  __shared__ float tile[32][33];
  int z = blockIdx.z;
  src += (long)z * srcBatch;
  dst += (long)z * dstBatch;
  int r0 = blockIdx.y * 32, c0 = blockIdx.x * 32;
  int tx = threadIdx.x & 31, ty = threadIdx.x >> 5;  // ty 0..7
#pragma unroll
  for (int i = 0; i < 4; ++i) {
    int rr = ty + i * 8;
    tile[rr][tx] = src[(long)(r0 + rr) * C + c0 + tx];
  }
  __syncthreads();
#pragma unroll
  for (int i = 0; i < 4; ++i) {
    int rr = ty + i * 8;
    dst[(long)(c0 + rr) * R + r0 + tx] = f2bf(tile[tx][rr]);
  }
}

// ---------------- fused bias for the reduce GEMM: biasf[r] = db1[r] + sum_i eb2[i]*dw1t[r][i] ----------------
__global__ __launch_bounds__(256) void k_bias_fused(
    const u16* __restrict__ dw1t, const float* __restrict__ eb2,
    const float* __restrict__ db1, float* __restrict__ biasf) {
  int r = blockIdx.x;  // 0..511
  const u16* row = dw1t + (long)r * 12800;
  float s = 0.f;
  for (int i = threadIdx.x; i < 12800; i += 256) s += bf2f(row[i]) * eb2[i];
  __shared__ float red[256];
  red[threadIdx.x] = s;
  __syncthreads();
  for (int off = 128; off > 0; off >>= 1) {
    if (threadIdx.x < off) red[threadIdx.x] += red[threadIdx.x + off];
    __syncthreads();
  }
  if (threadIdx.x == 0) biasf[r] = red[0] + db1[r];
}

// ---------------- concat two length-n fp32 vectors ----------------
__global__ __launch_bounds__(256) void k_concat2(const float* __restrict__ a,
                                                 const float* __restrict__ b,
                                                 float* __restrict__ dst, int n) {
  int i = blockIdx.x * 256 + threadIdx.x;
  if (i < n) dst[i] = a[i];
  else if (i < 2 * n) dst[i] = b[i - n];
}

// ---------------- core bf16 MFMA GEMM: C = A[M,K] @ Bt[N,K]^T (+bias, relu, rowscale) ----------------
// 128x128 tile, BK=32, 256 threads (4 waves 2x2, each 64x64 = 4x4 frags of 16x16x32).
// flags: 1 = relu, 2 = fp32 output (else bf16)
__global__ __launch_bounds__(256) void k_gemm(
    const u16* __restrict__ A, int lda, long aBatch,
    const u16* __restrict__ B, int ldb, long bBatch,   // B is Bt: [N][K]
    void* __restrict__ Cp, int ldc, long cBatch,
    int K,
    const float* __restrict__ bias, long biasBatch,
    const float* __restrict__ rowscale, int flags) {
  __shared__ __align__(16) u16 As[2][128 * 32];
  __shared__ __align__(16) u16 Bs[2][128 * 32];
  const int tid = threadIdx.x;
  const int w = tid >> 6, l = tid & 63;
  const int z = blockIdx.z;
  const u16* Ab = A + (long)z * aBatch + (long)blockIdx.y * 128 * lda;
  const u16* Bb = B + (long)z * bBatch + (long)blockIdx.x * 128 * ldb;
  const int ldaB = lda * 2, ldbB = ldb * 2;
  const int wm = w >> 1, wn = w & 1;
  const int r = l & 15, kq = l >> 4;

  // staging geometry: tile = 128 rows x 64 bytes = 8192B; 2 issues of 4096B
  const int f0 = w * 1024 + l * 16;
  const int f1 = f0 + 4096;
  const int row0 = f0 >> 6, cb0 = f0 & 63;
  const int row1 = f1 >> 6, cb1 = f1 & 63;
  const int seg0 = w * 1024, seg1 = seg0 + 4096;  // wave-uniform LDS dests

  v4f acc[4][4];
#pragma unroll
  for (int m = 0; m < 4; ++m)
#pragma unroll
    for (int n = 0; n < 4; ++n) acc[m][n] = v4f{0.f, 0.f, 0.f, 0.f};

  const char* gA = (const char*)Ab;
  const char* gB = (const char*)Bb;
  const int nkt = K / 32;

  // prologue: stage k-tile 0 into buffer 0
  async16(gA + (long)row0 * ldaB + cb0, (char*)As[0] + seg0);
  async16(gA + (long)row1 * ldaB + cb1, (char*)As[0] + seg1);
  async16(gB + (long)row0 * ldbB + cb0, (char*)Bs[0] + seg0);
  async16(gB + (long)row1 * ldbB + cb1, (char*)Bs[0] + seg1);
  __syncthreads();

  for (int kt = 0; kt < nkt; ++kt) {
    const int cur = kt & 1;
    if (kt + 1 < nkt) {
      const long ko = (long)(kt + 1) * 64;  // 32 bf16 = 64 bytes along K
      async16(gA + ko + (long)row0 * ldaB + cb0, (char*)As[cur ^ 1] + seg0);
      async16(gA + ko + (long)row1 * ldaB + cb1, (char*)As[cur ^ 1] + seg1);
      async16(gB + ko + (long)row0 * ldbB + cb0, (char*)Bs[cur ^ 1] + seg0);
      async16(gB + ko + (long)row1 * ldbB + cb1, (char*)Bs[cur ^ 1] + seg1);
    }
    v8bf af[4], bfr[4];
#pragma unroll
    for (int m = 0; m < 4; ++m)
      af[m] = *(const v8bf*)&As[cur][(wm * 64 + m * 16 + r) * 32 + kq * 8];
#pragma unroll
    for (int n = 0; n < 4; ++n)
      bfr[n] = *(const v8bf*)&Bs[cur][(wn * 64 + n * 16 + r) * 32 + kq * 8];
#pragma unroll
    for (int m = 0; m < 4; ++m)
#pragma unroll
      for (int n = 0; n < 4; ++n)
        acc[m][n] = __builtin_amdgcn_mfma_f32_16x16x32_bf16(af[m], bfr[n], acc[m][n], 0, 0, 0);
    __syncthreads();
  }

  // epilogue: C row = bm0 + wm*64 + m*16 + kq*4 + i ; col = bn0 + wn*64 + n*16 + r
  const float* bz = bias ? (bias + (long)z * biasBatch) : nullptr;
  const long rowBase = (long)blockIdx.y * 128 + wm * 64 + kq * 4;
  const int colBase = blockIdx.x * 128 + wn * 64 + r;
  float* Cf = (float*)Cp + (long)z * cBatch;
  u16* Ch = (u16*)Cp + (long)z * cBatch;
#pragma unroll
  for (int m = 0; m < 4; ++m) {
#pragma unroll
    for (int n = 0; n < 4; ++n) {
      const int col = colBase + n * 16;
      const float bv = bz ? bz[col] : 0.f;
#pragma unroll
      for (int i = 0; i < 4; ++i) {
        const long row = rowBase + m * 16 + i;
        float v = acc[m][n][i] + bv;
        if (flags & 1) v = fmaxf(v, 0.f);
        if (rowscale) v *= rowscale[row];
        const long idx = row * ldc + col;
        if (flags & 2) Cf[idx] = v;
        else Ch[idx] = f2bf(v);
      }
    }
  }
}

// ---------------- split-K reduce: dh = bf16(relu(sum_s part[s] + biasf[col])) ----------------
__global__ __launch_bounds__(256) void k_splitk_reduce(
    const float* __restrict__ part, const float* __restrict__ bias,
    u16* __restrict__ dst, int total, int S) {
  int i = blockIdx.x * 256 + threadIdx.x;
  if (i >= total) return;
  float s = 0.f;
  for (int k = 0; k < S; ++k) s += part[(long)k * total + i];
  s += bias[i & 511];  // ldc = 512
  dst[i] = f2bf(fmaxf(s, 0.f));
}

// ---------------- gating: g[n] = sigmoid(lat)*sigmoid(bwd) ----------------
__global__ __launch_bounds__(256) void k_gate(
    const u16* __restrict__ lbh,  // [2048][512]: cols 0-255 lat hidden, 256-511 bwd hidden
    const float* __restrict__ lw2, const float* __restrict__ lb2,
    const float* __restrict__ bw2, const float* __restrict__ bb2,
    float* __restrict__ g) {
  int w = threadIdx.x >> 6, l = threadIdx.x & 63;
  int n = blockIdx.x * 4 + w;
  const u16* rowp = lbh + (long)n * 512;
  float sa = 0.f, sb = 0.f;
#pragma unroll
  for (int j = 0; j < 4; ++j) {
    int i = l * 4 + j;
    sa += bf2f(rowp[i]) * lw2[i];
    sb += bf2f(rowp[256 + i]) * bw2[i];
  }
#pragma unroll
  for (int off = 32; off > 0; off >>= 1) {
    sa += __shfl_down(sa, off, 64);
    sb += __shfl_down(sb, off, 64);
  }
  if (l == 0) {
    float ga = 1.f / (1.f + expf(-(sa + lb2[0])));
    float gb = 1.f / (1.f + expf(-(sb + bb2[0])));
    g[n] = ga * gb;
  }
}

extern "C" void kernel_launch(void* const* d_in, const int* in_sizes, int n_in,
                              void* d_out, int out_size, void* d_ws, size_t ws_size,
                              hipStream_t stream) {
  const float* x   = (const float*)d_in[0];
  const float* ew1 = (const float*)d_in[1];
  const float* eb1 = (const float*)d_in[2];
  const float* ew2 = (const float*)d_in[3];
  const float* eb2 = (const float*)d_in[4];
  const float* dw1 = (const float*)d_in[5];
  const float* db1 = (const float*)d_in[6];
  const float* dw2 = (const float*)d_in[7];
  const float* db2 = (const float*)d_in[8];
  const float* lw1 = (const float*)d_in[9];
  const float* lb1 = (const float*)d_in[10];
  const float* lw2 = (const float*)d_in[11];
  const float* lb2 = (const float*)d_in[12];
  const float* bw1 = (const float*)d_in[13];
  const float* bb1 = (const float*)d_in[14];
  const float* bw2 = (const float*)d_in[15];
  const float* bb2 = (const float*)d_in[16];
  const float* pw1 = (const float*)d_in[17];
  const float* pb1 = (const float*)d_in[18];
  const float* pw2 = (const float*)d_in[19];
  const float* pb2 = (const float*)d_in[20];

  // N=2048, DIN=1024, DOUT=256, E=50, H=256, RH=512, EH=E*H=12800
  char* p = (char*)d_ws;
  auto alloc = [&](size_t bytes) {
    char* q = p;
    p += (bytes + 255) & ~(size_t)255;
    return q;
  };
  u16* xb      = (u16*)alloc((size_t)2048 * 1024 * 2);
  u16* ew1t    = (u16*)alloc((size_t)12800 * 1024 * 2);
  u16* Wft     = (u16*)alloc((size_t)512 * 12800 * 2);
  u16* dw2t    = (u16*)alloc((size_t)256 * 512 * 2);
  u16* lbw1t   = (u16*)alloc((size_t)512 * 1024 * 2);
  u16* pw1t    = (u16*)alloc((size_t)256 * 256 * 2);
  u16* pw2t    = (u16*)alloc((size_t)256 * 256 * 2);
  float* biasf   = (float*)alloc(512 * 4);
  float* biascat = (float*)alloc(512 * 4);
  u16* dh      = (u16*)alloc((size_t)2048 * 512 * 2);
  u16* dist    = (u16*)alloc((size_t)2048 * 256 * 2);
  u16* lbh     = (u16*)alloc((size_t)2048 * 512 * 2);
  float* g     = (float*)alloc(2048 * 4);
  u16* ph      = (u16*)alloc((size_t)2048 * 256 * 2);
  float* part  = (float*)alloc((size_t)8 * 2048 * 512 * 4);  // split-K partials
  // union region: {ew2b, dw1t} (precompute-only) aliased under h_all (written later)
  char* uni    = alloc((size_t)2048 * 12800 * 2);
  u16* h_all   = (u16*)uni;
  u16* ew2b    = (u16*)uni;
  u16* dw1t    = (u16*)(uni + (((size_t)50 * 256 * 256 * 2 + 255) & ~(size_t)255));
  (void)ws_size; (void)in_sizes; (void)n_in; (void)out_size;

  // --- precompute: bf16 conversions / transposes ---
  k_f2b<<<dim3(2048), 256, 0, stream>>>(x, xb, 2048 * 1024);
  k_f2b<<<dim3(3200), 256, 0, stream>>>(ew2, ew2b, 50 * 256 * 256);
  k_transpose_f2b<<<dim3(8, 32, 50), 256, 0, stream>>>(ew1, ew1t, 1024, 256, 1024 * 256, 256 * 1024);
  k_transpose_f2b<<<dim3(16, 400, 1), 256, 0, stream>>>(dw1, dw1t, 12800, 512, 0, 0);
  k_transpose_f2b<<<dim3(8, 16, 1), 256, 0, stream>>>(dw2, dw2t, 512, 256, 0, 0);
  k_transpose_f2b<<<dim3(8, 32, 1), 256, 0, stream>>>(lw1, lbw1t, 1024, 256, 0, 0);
  k_transpose_f2b<<<dim3(8, 32, 1), 256, 0, stream>>>(bw1, lbw1t + 256 * 1024, 1024, 256, 0, 0);
  k_transpose_f2b<<<dim3(8, 8, 1), 256, 0, stream>>>(pw1, pw1t, 256, 256, 0, 0);
  k_transpose_f2b<<<dim3(8, 8, 1), 256, 0, stream>>>(pw2, pw2t, 256, 256, 0, 0);
  k_bias_fused<<<dim3(512), 256, 0, stream>>>(dw1t, eb2, db1, biasf);
  k_concat2<<<dim3(2), 256, 0, stream>>>(lb1, bb1, biascat, 256);

  // --- Wft[e] = dw1_e^T @ ew2_e^T  (batched, M=512,N=256,K=256) -> Wft [512][12800] bf16 ---
  k_gemm<<<dim3(2, 4, 50), 256, 0, stream>>>(
      dw1t, 12800, 256, ew2b, 256, (long)256 * 256, Wft, 12800, 256,
      256, nullptr, 0, nullptr, 0);

  // --- GEMM1: h_all = relu(xb @ ew1t^T + eb1)  M=2048,N=12800,K=1024, bf16 out ---
  k_gemm<<<dim3(100, 16, 1), 256, 0, stream>>>(
      xb, 1024, 0, ew1t, 1024, 0, h_all, 12800, 0,
      1024, eb1, 0, nullptr, 1);

  // --- reduce GEMM (split-K S=8): part[s] = h_all[:,s] @ Wft[:,s]^T  (fp32 raw) ---
  k_gemm<<<dim3(4, 16, 8), 256, 0, stream>>>(
      h_all, 12800, 1600, Wft, 12800, 1600, part, 512, (long)2048 * 512,
      1600, nullptr, 0, nullptr, 2);
  k_splitk_reduce<<<dim3(4096), 256, 0, stream>>>(part, biasf, dh, 2048 * 512, 8);

  // --- dist = dh @ dw2t^T + db2  (M=2048,N=256,K=512) ---
  k_gemm<<<dim3(2, 16, 1), 256, 0, stream>>>(
      dh, 512, 0, dw2t, 512, 0, dist, 256, 0, 512, db2, 0, nullptr, 0);

  // --- gating hidden: lbh = relu(xb @ [lw1|bw1] + [lb1|bb1])  (M=2048,N=512,K=1024) ---
  k_gemm<<<dim3(4, 16, 1), 256, 0, stream>>>(
      xb, 1024, 0, lbw1t, 1024, 0, lbh, 512, 0, 1024, biascat, 0, nullptr, 1);
  k_gate<<<dim3(512), 256, 0, stream>>>(lbh, lw2, lb2, bw2, bb2, g);

  // --- privacy: ph = relu(dist @ pw1t^T + pb1); out = (ph @ pw2t^T + pb2) * g[row] ---
  k_gemm<<<dim3(2, 16, 1), 256, 0, stream>>>(
      dist, 256, 0, pw1t, 256, 0, ph, 256, 0, 256, pb1, 0, nullptr, 1);
  k_gemm<<<dim3(2, 16, 1), 256, 0, stream>>>(
      ph, 256, 0, pw2t, 256, 0, (float*)d_out, 256, 0, 256, pb2, 0, g, 2);
}